// Round 2
// baseline (931.157 us; speedup 1.0000x reference)
//
#include <hip/hip_runtime.h>
#include <math.h>

#define NN 50000
#define NE 1000000
#define NH 64

// ---------- pass A: degree histograms ---------------------------------------
__global__ __launch_bounds__(256) void hist_kernel(
    const int* __restrict__ src, const int* __restrict__ dst,
    int* __restrict__ hist_src, int* __restrict__ hist_dst) {
    int tid = blockIdx.x * blockDim.x + threadIdx.x;
    if (tid >= NE) return;
    atomicAdd(&hist_src[src[tid]], 1);
    atomicAdd(&hist_dst[dst[tid]], 1);
}

// ---------- pass B: exclusive scan (single block) ---------------------------
__device__ void scan_one(const int* __restrict__ hist, int* __restrict__ off,
                         int* __restrict__ cur, int* tmp) {
    const int T = 1024;
    const int CH = (NN + T - 1) / T;  // 49
    int t = threadIdx.x;
    int lo = t * CH, hi = min(lo + CH, NN);
    int s = 0;
    for (int i = lo; i < hi; ++i) s += hist[i];
    tmp[t] = s;
    __syncthreads();
    for (int o = 1; o < T; o <<= 1) {   // Hillis-Steele inclusive scan
        int v = (t >= o) ? tmp[t - o] : 0;
        __syncthreads();
        tmp[t] += v;
        __syncthreads();
    }
    int run = tmp[t] - s;  // exclusive prefix of this chunk
    for (int i = lo; i < hi; ++i) {
        off[i] = run; cur[i] = run;
        run += hist[i];
    }
    if (t == T - 1) off[NN] = run;  // == NE
    __syncthreads();
}

__global__ __launch_bounds__(1024) void scan_kernel(
    const int* __restrict__ hist_src, const int* __restrict__ hist_dst,
    int* __restrict__ off_src, int* __restrict__ cur_src,
    int* __restrict__ off_dst, int* __restrict__ cur_dst) {
    __shared__ int tmp[1024];
    scan_one(hist_src, off_src, cur_src, tmp);
    __syncthreads();
    scan_one(hist_dst, off_dst, cur_dst, tmp);
}

// ---------- pass C: CSR build (counting-sort scatter) -----------------------
__global__ __launch_bounds__(256) void build_kernel(
    const int* __restrict__ src, const int* __restrict__ dst,
    int* __restrict__ cur_src, int* __restrict__ cur_dst,
    int* __restrict__ csr_src, int* __restrict__ csr_dst) {
    int tid = blockIdx.x * blockDim.x + threadIdx.x;
    if (tid >= NE) return;
    int s = src[tid], d = dst[tid];
    int p = atomicAdd(&cur_src[s], 1); csr_src[p] = d;  // out-edges of s: dst
    int q = atomicAdd(&cur_dst[d], 1); csr_dst[q] = s;  // in-edges of d: src
}

// ---------- pass D: gather-mean + SAGE + projections, fused -----------------
__global__ __launch_bounds__(256) void node_pass(
    const float* __restrict__ X, const int* __restrict__ off_dst,
    const int* __restrict__ csr_dst,
    const float* __restrict__ Wself, const float* __restrict__ Wneigh,
    const float* __restrict__ bsage, const float* __restrict__ Qw,
    float* __restrict__ A, float* __restrict__ B) {
    __shared__ float sWs[64 * 64];
    __shared__ float sWn[64 * 64];
    __shared__ float sQ1[64 * 64];
    __shared__ float sQ2[64 * 64];
    __shared__ float sx[4][64];
    __shared__ float sm[4][64];
    __shared__ float sh[4][64];

    for (int i = threadIdx.x; i < 64 * 64; i += 256) {
        sWs[i] = Wself[i];
        sWn[i] = Wneigh[i];
        sQ1[i] = Qw[i];            // rows 0..63 of Q_w
        sQ2[i] = Qw[4096 + i];     // rows 64..127
    }
    __syncthreads();

    int sub = threadIdx.x >> 6;
    int j   = threadIdx.x & 63;
    float bj = bsage[j];

    for (int base = blockIdx.x * 4; base < NN; base += gridDim.x * 4) {
        int node = base + sub;
        if (node < NN) {
            int e0 = off_dst[node], e1 = off_dst[node + 1];
            float sum = 0.0f;
            for (int e = e0; e < e1; ++e) {
                int sv = csr_dst[e];                 // wave-uniform broadcast
                sum += X[(size_t)sv * NH + j];       // coalesced 256B row
            }
            sx[sub][j] = X[(size_t)node * NH + j];
            sm[sub][j] = sum / fmaxf((float)(e1 - e0), 1.0f);
        }
        __syncthreads();
        if (node < NN) {
            float acc = bj;
            #pragma unroll
            for (int k = 0; k < 64; ++k)
                acc += sx[sub][k] * sWs[k * 64 + j] + sm[sub][k] * sWn[k * 64 + j];
            sh[sub][j] = fmaxf(acc, 0.0f);
        }
        __syncthreads();
        if (node < NN) {
            float a = 0.0f, b = 0.0f;
            #pragma unroll
            for (int k = 0; k < 64; ++k) {
                float h = sh[sub][k];
                a += h * sQ1[k * 64 + j];
                b += h * sQ2[k * 64 + j];
            }
            A[(size_t)node * NH + j] = a;
            B[(size_t)node * NH + j] = b;
        }
        __syncthreads();
    }
}

// ---------- pass E: per-node out-edge reduction + tanh, fully fused ---------
__global__ __launch_bounds__(256) void edge_out(
    const float* __restrict__ A, const float* __restrict__ B,
    const float* __restrict__ Qb, const int* __restrict__ off_src,
    const int* __restrict__ csr_src, float* __restrict__ out) {
    int wid = (int)(((long long)blockIdx.x * blockDim.x + threadIdx.x) >> 6);
    int j = threadIdx.x & 63;
    if (wid >= NN) return;
    float a = A[(size_t)wid * NH + j] + Qb[j];
    int e0 = off_src[wid], e1 = off_src[wid + 1];
    float acc = 0.0f;
    for (int e = e0; e < e1; ++e) {
        int d = csr_src[e];                          // wave-uniform broadcast
        float t = a + B[(size_t)d * NH + j];         // coalesced 256B row
        acc += t * t;
    }
    out[(size_t)wid * NH + j] = tanhf(acc / fmaxf((float)(e1 - e0), 1.0f));
}

extern "C" void kernel_launch(void* const* d_in, const int* in_sizes, int n_in,
                              void* d_out, int out_size, void* d_ws, size_t ws_size,
                              hipStream_t stream) {
    const float* X      = (const float*)d_in[0];
    const int*   ei     = (const int*)d_in[1];   // [2, NE] int32
    const float* Wself  = (const float*)d_in[2];
    const float* Wneigh = (const float*)d_in[3];
    const float* bsage  = (const float*)d_in[4];
    const float* Qw     = (const float*)d_in[5];
    const float* Qb     = (const float*)d_in[6];
    const int* src = ei;
    const int* dst = ei + NE;

    float* out = (float*)d_out;

    // workspace layout
    float* ws   = (float*)d_ws;
    float* A    = ws;                          // NN*NH floats
    float* B    = A + (size_t)NN * NH;         // NN*NH floats
    int* ibase    = (int*)(B + (size_t)NN * NH);
    int* hist_src = ibase;                     // NN  (contiguous with hist_dst
    int* hist_dst = ibase + NN;                // NN   for a single memset)
    int* off_src  = ibase + 2 * NN;            // NN+1
    int* off_dst  = off_src + NN + 1;          // NN+1
    int* cur_src  = off_dst + NN + 1;          // NN
    int* cur_dst  = cur_src + NN;              // NN
    int* csr_src  = cur_dst + NN;              // NE
    int* csr_dst  = csr_src + NE;              // NE

    hipMemsetAsync(hist_src, 0, (size_t)2 * NN * sizeof(int), stream);

    hist_kernel<<<(NE + 255) / 256, 256, 0, stream>>>(src, dst, hist_src, hist_dst);
    scan_kernel<<<1, 1024, 0, stream>>>(hist_src, hist_dst, off_src, cur_src,
                                        off_dst, cur_dst);
    build_kernel<<<(NE + 255) / 256, 256, 0, stream>>>(src, dst, cur_src, cur_dst,
                                                       csr_src, csr_dst);
    node_pass<<<2048, 256, 0, stream>>>(X, off_dst, csr_dst, Wself, Wneigh, bsage,
                                        Qw, A, B);
    edge_out<<<(NN * 64 + 255) / 256, 256, 0, stream>>>(A, B, Qb, off_src, csr_src,
                                                        out);
}

// Round 3
// 632.457 us; speedup vs baseline: 1.4723x; 1.4723x over previous
//
#include <hip/hip_runtime.h>
#include <math.h>

#define NN 50000
#define NE 1000000
#define NH 64

// ---------- pass A: degree histograms ---------------------------------------
__global__ __launch_bounds__(256) void hist_kernel(
    const int* __restrict__ src, const int* __restrict__ dst,
    int* __restrict__ hist_src, int* __restrict__ hist_dst) {
    int tid = blockIdx.x * blockDim.x + threadIdx.x;
    if (tid >= NE) return;
    atomicAdd(&hist_src[src[tid]], 1);
    atomicAdd(&hist_dst[dst[tid]], 1);
}

// ---------- pass B: exclusive scan (single block) ---------------------------
__device__ void scan_one(const int* __restrict__ hist, int* __restrict__ off,
                         int* __restrict__ cur, int* tmp) {
    const int T = 1024;
    const int CH = (NN + T - 1) / T;  // 49
    int t = threadIdx.x;
    int lo = t * CH, hi = min(lo + CH, NN);
    int s = 0;
    for (int i = lo; i < hi; ++i) s += hist[i];
    tmp[t] = s;
    __syncthreads();
    for (int o = 1; o < T; o <<= 1) {   // Hillis-Steele inclusive scan
        int v = (t >= o) ? tmp[t - o] : 0;
        __syncthreads();
        tmp[t] += v;
        __syncthreads();
    }
    int run = tmp[t] - s;  // exclusive prefix of this chunk
    for (int i = lo; i < hi; ++i) {
        off[i] = run; cur[i] = run;
        run += hist[i];
    }
    if (t == T - 1) off[NN] = run;  // == NE
    __syncthreads();
}

__global__ __launch_bounds__(1024) void scan_kernel(
    const int* __restrict__ hist_src, const int* __restrict__ hist_dst,
    int* __restrict__ off_src, int* __restrict__ cur_src,
    int* __restrict__ off_dst, int* __restrict__ cur_dst) {
    __shared__ int tmp[1024];
    scan_one(hist_src, off_src, cur_src, tmp);
    __syncthreads();
    scan_one(hist_dst, off_dst, cur_dst, tmp);
}

// ---------- pass C: CSR build (counting-sort scatter) -----------------------
__global__ __launch_bounds__(256) void build_kernel(
    const int* __restrict__ src, const int* __restrict__ dst,
    int* __restrict__ cur_src, int* __restrict__ cur_dst,
    int* __restrict__ csr_src, int* __restrict__ csr_dst) {
    int tid = blockIdx.x * blockDim.x + threadIdx.x;
    if (tid >= NE) return;
    int s = src[tid], d = dst[tid];
    int p = atomicAdd(&cur_src[s], 1); csr_src[p] = d;  // out-edges of s: dst
    int q = atomicAdd(&cur_dst[d], 1); csr_dst[q] = s;  // in-edges of d: src
}

// ---------- pass D: wave-per-node gather-mean, 8-deep ILP -------------------
__global__ __launch_bounds__(256) void gather_mean(
    const float* __restrict__ X, const int* __restrict__ off_dst,
    const int* __restrict__ csr_dst, float* __restrict__ M) {
    int wid = (int)(((long long)blockIdx.x * blockDim.x + threadIdx.x) >> 6);
    int j = threadIdx.x & 63;
    if (wid >= NN) return;
    int e0 = off_dst[wid], e1 = off_dst[wid + 1];
    const float* Xj = X + j;
    float s0 = 0, s1 = 0, s2 = 0, s3 = 0, s4 = 0, s5 = 0, s6 = 0, s7 = 0;
    int e = e0;
    for (; e + 8 <= e1; e += 8) {
        int i0 = csr_dst[e + 0], i1 = csr_dst[e + 1];
        int i2 = csr_dst[e + 2], i3 = csr_dst[e + 3];
        int i4 = csr_dst[e + 4], i5 = csr_dst[e + 5];
        int i6 = csr_dst[e + 6], i7 = csr_dst[e + 7];
        s0 += Xj[(size_t)i0 * NH]; s1 += Xj[(size_t)i1 * NH];
        s2 += Xj[(size_t)i2 * NH]; s3 += Xj[(size_t)i3 * NH];
        s4 += Xj[(size_t)i4 * NH]; s5 += Xj[(size_t)i5 * NH];
        s6 += Xj[(size_t)i6 * NH]; s7 += Xj[(size_t)i7 * NH];
    }
    for (; e < e1; ++e) s0 += Xj[(size_t)csr_dst[e] * NH];
    float sum = ((s0 + s1) + (s2 + s3)) + ((s4 + s5) + (s6 + s7));
    M[(size_t)wid * NH + j] = sum / fmaxf((float)(e1 - e0), 1.0f);
}

// ---------- pass E: wave-local SAGE + projections (no inner barriers) -------
__global__ __launch_bounds__(256) void node_gemm(
    const float* __restrict__ X, float* MA /* in: mean, out: A (aliased) */,
    const float* __restrict__ Wself, const float* __restrict__ Wneigh,
    const float* __restrict__ bsage, const float* __restrict__ Qw,
    float* __restrict__ B) {
    __shared__ float sWs[4096];
    __shared__ float sWn[4096];
    __shared__ float sQ1[4096];
    __shared__ float sQ2[4096];
    __shared__ float st[4][3][64];   // per-wave x, m, h staging

    for (int i = threadIdx.x; i < 4096; i += 256) {
        sWs[i] = Wself[i];
        sWn[i] = Wneigh[i];
        sQ1[i] = Qw[i];            // rows 0..63 of Q_w
        sQ2[i] = Qw[4096 + i];     // rows 64..127
    }
    __syncthreads();

    int w = threadIdx.x >> 6;
    int j = threadIdx.x & 63;
    float bj = bsage[j];

    for (int node = blockIdx.x * 4 + w; node < NN; node += gridDim.x * 4) {
        st[w][0][j] = X[(size_t)node * NH + j];
        st[w][1][j] = MA[(size_t)node * NH + j];
        __builtin_amdgcn_wave_barrier();   // wave-synchronous LDS RAW
        float acc = bj;
        #pragma unroll
        for (int k = 0; k < 64; ++k)
            acc += st[w][0][k] * sWs[k * 64 + j] + st[w][1][k] * sWn[k * 64 + j];
        float h = fmaxf(acc, 0.0f);
        st[w][2][j] = h;
        __builtin_amdgcn_wave_barrier();
        float a = 0.0f, b = 0.0f;
        #pragma unroll
        for (int k = 0; k < 64; ++k) {
            float hk = st[w][2][k];
            a += hk * sQ1[k * 64 + j];
            b += hk * sQ2[k * 64 + j];
        }
        MA[(size_t)node * NH + j] = a;     // overwrite mean with A (1:1, safe)
        B[(size_t)node * NH + j] = b;
        __builtin_amdgcn_wave_barrier();   // keep next iter's write after reads
    }
}

// ---------- pass F: wave-per-node out-edge reduction, 8-deep ILP ------------
__global__ __launch_bounds__(256) void edge_out(
    const float* __restrict__ A, const float* __restrict__ B,
    const float* __restrict__ Qb, const int* __restrict__ off_src,
    const int* __restrict__ csr_src, float* __restrict__ out) {
    int wid = (int)(((long long)blockIdx.x * blockDim.x + threadIdx.x) >> 6);
    int j = threadIdx.x & 63;
    if (wid >= NN) return;
    float aq = A[(size_t)wid * NH + j] + Qb[j];
    int e0 = off_src[wid], e1 = off_src[wid + 1];
    const float* Bj = B + j;
    float s0 = 0, s1 = 0, s2 = 0, s3 = 0, s4 = 0, s5 = 0, s6 = 0, s7 = 0;
    int e = e0;
    for (; e + 8 <= e1; e += 8) {
        int i0 = csr_src[e + 0], i1 = csr_src[e + 1];
        int i2 = csr_src[e + 2], i3 = csr_src[e + 3];
        int i4 = csr_src[e + 4], i5 = csr_src[e + 5];
        int i6 = csr_src[e + 6], i7 = csr_src[e + 7];
        float t0 = aq + Bj[(size_t)i0 * NH]; s0 += t0 * t0;
        float t1 = aq + Bj[(size_t)i1 * NH]; s1 += t1 * t1;
        float t2 = aq + Bj[(size_t)i2 * NH]; s2 += t2 * t2;
        float t3 = aq + Bj[(size_t)i3 * NH]; s3 += t3 * t3;
        float t4 = aq + Bj[(size_t)i4 * NH]; s4 += t4 * t4;
        float t5 = aq + Bj[(size_t)i5 * NH]; s5 += t5 * t5;
        float t6 = aq + Bj[(size_t)i6 * NH]; s6 += t6 * t6;
        float t7 = aq + Bj[(size_t)i7 * NH]; s7 += t7 * t7;
    }
    for (; e < e1; ++e) {
        float t = aq + Bj[(size_t)csr_src[e] * NH];
        s0 += t * t;
    }
    float acc = ((s0 + s1) + (s2 + s3)) + ((s4 + s5) + (s6 + s7));
    out[(size_t)wid * NH + j] = tanhf(acc / fmaxf((float)(e1 - e0), 1.0f));
}

extern "C" void kernel_launch(void* const* d_in, const int* in_sizes, int n_in,
                              void* d_out, int out_size, void* d_ws, size_t ws_size,
                              hipStream_t stream) {
    const float* X      = (const float*)d_in[0];
    const int*   ei     = (const int*)d_in[1];   // [2, NE] int32
    const float* Wself  = (const float*)d_in[2];
    const float* Wneigh = (const float*)d_in[3];
    const float* bsage  = (const float*)d_in[4];
    const float* Qw     = (const float*)d_in[5];
    const float* Qb     = (const float*)d_in[6];
    const int* src = ei;
    const int* dst = ei + NE;

    float* out = (float*)d_out;

    // workspace layout (34.8 MB total)
    float* ws   = (float*)d_ws;
    float* A    = ws;                          // NN*NH floats (also holds mean)
    float* B    = A + (size_t)NN * NH;         // NN*NH floats
    int* ibase    = (int*)(B + (size_t)NN * NH);
    int* hist_src = ibase;                     // NN
    int* hist_dst = ibase + NN;                // NN
    int* off_src  = ibase + 2 * NN;            // NN+1
    int* off_dst  = off_src + NN + 1;          // NN+1
    int* cur_src  = off_dst + NN + 1;          // NN
    int* cur_dst  = cur_src + NN;              // NN
    int* csr_src  = cur_dst + NN;              // NE
    int* csr_dst  = csr_src + NE;              // NE

    hipMemsetAsync(hist_src, 0, (size_t)2 * NN * sizeof(int), stream);

    hist_kernel<<<(NE + 255) / 256, 256, 0, stream>>>(src, dst, hist_src, hist_dst);
    scan_kernel<<<1, 1024, 0, stream>>>(hist_src, hist_dst, off_src, cur_src,
                                        off_dst, cur_dst);
    build_kernel<<<(NE + 255) / 256, 256, 0, stream>>>(src, dst, cur_src, cur_dst,
                                                       csr_src, csr_dst);
    gather_mean<<<(NN + 3) / 4, 256, 0, stream>>>(X, off_dst, csr_dst, A);
    node_gemm<<<512, 256, 0, stream>>>(X, A, Wself, Wneigh, bsage, Qw, B);
    edge_out<<<(NN + 3) / 4, 256, 0, stream>>>(A, B, Qb, off_src, csr_src, out);
}

// Round 4
// 422.252 us; speedup vs baseline: 2.2052x; 1.4978x over previous
//
#include <hip/hip_runtime.h>
#include <math.h>

#define NN 50000
#define NE 1000000
#define NH 64
#define NB 98            // ceil(2*NN / 1024)

// ---------- pass A: degree histograms (concatenated src|dst) ----------------
__global__ __launch_bounds__(256) void hist_kernel(
    const int* __restrict__ src, const int* __restrict__ dst,
    int* __restrict__ hist) {
    int tid = blockIdx.x * blockDim.x + threadIdx.x;
    if (tid >= NE) return;
    atomicAdd(&hist[src[tid]], 1);
    atomicAdd(&hist[NN + dst[tid]], 1);
}

// ---------- pass B1: per-block partial sums ---------------------------------
__global__ __launch_bounds__(1024) void scan_partial(
    const int* __restrict__ hist, int* __restrict__ bsum) {
    __shared__ int tmp[1024];
    int t = threadIdx.x;
    int g = blockIdx.x * 1024 + t;
    tmp[t] = (g < 2 * NN) ? hist[g] : 0;
    __syncthreads();
    for (int o = 512; o > 0; o >>= 1) {
        if (t < o) tmp[t] += tmp[t + o];
        __syncthreads();
    }
    if (t == 0) bsum[blockIdx.x] = tmp[0];
}

// ---------- pass B2: scan the 98 block sums (single tiny block) -------------
__global__ __launch_bounds__(128) void scan_bsums(
    const int* __restrict__ bsum, int* __restrict__ bpre) {
    __shared__ int tmp[128];
    int t = threadIdx.x;
    int v = (t < NB) ? bsum[t] : 0;
    tmp[t] = v;
    __syncthreads();
    for (int o = 1; o < 128; o <<= 1) {
        int u = (t >= o) ? tmp[t - o] : 0;
        __syncthreads();
        tmp[t] += u;
        __syncthreads();
    }
    if (t < NB) bpre[t] = tmp[t] - v;   // exclusive prefix
}

// ---------- pass B3: per-block exclusive scan + block offset ----------------
__global__ __launch_bounds__(1024) void scan_final(
    const int* __restrict__ hist, const int* __restrict__ bpre,
    int* __restrict__ off, int* __restrict__ cur) {
    __shared__ int tmp[1024];
    int t = threadIdx.x;
    int g = blockIdx.x * 1024 + t;
    int v = (g < 2 * NN) ? hist[g] : 0;
    tmp[t] = v;
    __syncthreads();
    for (int o = 1; o < 1024; o <<= 1) {
        int u = (t >= o) ? tmp[t - o] : 0;
        __syncthreads();
        tmp[t] += u;
        __syncthreads();
    }
    int ex = tmp[t] - v + bpre[blockIdx.x];
    if (g < 2 * NN) { off[g] = ex; cur[g] = ex; }
    if (g == 2 * NN - 1) off[2 * NN] = ex + v;   // == 2*NE
}

// ---------- pass C: CSR build (counting-sort scatter into one 2*NE array) ---
__global__ __launch_bounds__(256) void build_kernel(
    const int* __restrict__ src, const int* __restrict__ dst,
    int* __restrict__ cur, int* __restrict__ csr) {
    int tid = blockIdx.x * blockDim.x + threadIdx.x;
    if (tid >= NE) return;
    int s = src[tid], d = dst[tid];
    int p = atomicAdd(&cur[s], 1);      csr[p] = d;  // out-edges of s
    int q = atomicAdd(&cur[NN + d], 1); csr[q] = s;  // in-edges of d
}

// ---------- pass D: wave-per-node gather-mean, 8-deep ILP -------------------
__global__ __launch_bounds__(256) void gather_mean(
    const float* __restrict__ X, const int* __restrict__ off_dst,
    const int* __restrict__ csr, float* __restrict__ M) {
    int wid = (int)(((long long)blockIdx.x * blockDim.x + threadIdx.x) >> 6);
    int j = threadIdx.x & 63;
    if (wid >= NN) return;
    int e0 = off_dst[wid], e1 = off_dst[wid + 1];
    const float* Xj = X + j;
    float s0 = 0, s1 = 0, s2 = 0, s3 = 0, s4 = 0, s5 = 0, s6 = 0, s7 = 0;
    int e = e0;
    for (; e + 8 <= e1; e += 8) {
        int i0 = csr[e + 0], i1 = csr[e + 1];
        int i2 = csr[e + 2], i3 = csr[e + 3];
        int i4 = csr[e + 4], i5 = csr[e + 5];
        int i6 = csr[e + 6], i7 = csr[e + 7];
        s0 += Xj[(size_t)i0 * NH]; s1 += Xj[(size_t)i1 * NH];
        s2 += Xj[(size_t)i2 * NH]; s3 += Xj[(size_t)i3 * NH];
        s4 += Xj[(size_t)i4 * NH]; s5 += Xj[(size_t)i5 * NH];
        s6 += Xj[(size_t)i6 * NH]; s7 += Xj[(size_t)i7 * NH];
    }
    for (; e < e1; ++e) s0 += Xj[(size_t)csr[e] * NH];
    float sum = ((s0 + s1) + (s2 + s3)) + ((s4 + s5) + (s6 + s7));
    M[(size_t)wid * NH + j] = sum / fmaxf((float)(e1 - e0), 1.0f);
}

// ---------- pass E: wave-local SAGE + projections (no inner barriers) -------
__global__ __launch_bounds__(256) void node_gemm(
    const float* __restrict__ X, float* MA /* in: mean, out: A (aliased) */,
    const float* __restrict__ Wself, const float* __restrict__ Wneigh,
    const float* __restrict__ bsage, const float* __restrict__ Qw,
    float* __restrict__ B) {
    __shared__ float sWs[4096];
    __shared__ float sWn[4096];
    __shared__ float sQ1[4096];
    __shared__ float sQ2[4096];
    __shared__ float st[4][3][64];   // per-wave x, m, h staging

    for (int i = threadIdx.x; i < 4096; i += 256) {
        sWs[i] = Wself[i];
        sWn[i] = Wneigh[i];
        sQ1[i] = Qw[i];            // rows 0..63 of Q_w
        sQ2[i] = Qw[4096 + i];     // rows 64..127
    }
    __syncthreads();

    int w = threadIdx.x >> 6;
    int j = threadIdx.x & 63;
    float bj = bsage[j];

    for (int node = blockIdx.x * 4 + w; node < NN; node += gridDim.x * 4) {
        st[w][0][j] = X[(size_t)node * NH + j];
        st[w][1][j] = MA[(size_t)node * NH + j];
        __builtin_amdgcn_wave_barrier();   // wave-synchronous LDS RAW
        float acc = bj;
        #pragma unroll
        for (int k = 0; k < 64; ++k)
            acc += st[w][0][k] * sWs[k * 64 + j] + st[w][1][k] * sWn[k * 64 + j];
        float h = fmaxf(acc, 0.0f);
        st[w][2][j] = h;
        __builtin_amdgcn_wave_barrier();
        float a = 0.0f, b = 0.0f;
        #pragma unroll
        for (int k = 0; k < 64; ++k) {
            float hk = st[w][2][k];
            a += hk * sQ1[k * 64 + j];
            b += hk * sQ2[k * 64 + j];
        }
        MA[(size_t)node * NH + j] = a;     // overwrite mean with A (1:1, safe)
        B[(size_t)node * NH + j] = b;
        __builtin_amdgcn_wave_barrier();   // keep next iter's write after reads
    }
}

// ---------- pass F: wave-per-node out-edge reduction, 8-deep ILP ------------
__global__ __launch_bounds__(256) void edge_out(
    const float* __restrict__ A, const float* __restrict__ B,
    const float* __restrict__ Qb, const int* __restrict__ off_src,
    const int* __restrict__ csr, float* __restrict__ out) {
    int wid = (int)(((long long)blockIdx.x * blockDim.x + threadIdx.x) >> 6);
    int j = threadIdx.x & 63;
    if (wid >= NN) return;
    float aq = A[(size_t)wid * NH + j] + Qb[j];
    int e0 = off_src[wid], e1 = off_src[wid + 1];
    const float* Bj = B + j;
    float s0 = 0, s1 = 0, s2 = 0, s3 = 0, s4 = 0, s5 = 0, s6 = 0, s7 = 0;
    int e = e0;
    for (; e + 8 <= e1; e += 8) {
        int i0 = csr[e + 0], i1 = csr[e + 1];
        int i2 = csr[e + 2], i3 = csr[e + 3];
        int i4 = csr[e + 4], i5 = csr[e + 5];
        int i6 = csr[e + 6], i7 = csr[e + 7];
        float t0 = aq + Bj[(size_t)i0 * NH]; s0 += t0 * t0;
        float t1 = aq + Bj[(size_t)i1 * NH]; s1 += t1 * t1;
        float t2 = aq + Bj[(size_t)i2 * NH]; s2 += t2 * t2;
        float t3 = aq + Bj[(size_t)i3 * NH]; s3 += t3 * t3;
        float t4 = aq + Bj[(size_t)i4 * NH]; s4 += t4 * t4;
        float t5 = aq + Bj[(size_t)i5 * NH]; s5 += t5 * t5;
        float t6 = aq + Bj[(size_t)i6 * NH]; s6 += t6 * t6;
        float t7 = aq + Bj[(size_t)i7 * NH]; s7 += t7 * t7;
    }
    for (; e < e1; ++e) {
        float t = aq + Bj[(size_t)csr[e] * NH];
        s0 += t * t;
    }
    float acc = ((s0 + s1) + (s2 + s3)) + ((s4 + s5) + (s6 + s7));
    out[(size_t)wid * NH + j] = tanhf(acc / fmaxf((float)(e1 - e0), 1.0f));
}

extern "C" void kernel_launch(void* const* d_in, const int* in_sizes, int n_in,
                              void* d_out, int out_size, void* d_ws, size_t ws_size,
                              hipStream_t stream) {
    const float* X      = (const float*)d_in[0];
    const int*   ei     = (const int*)d_in[1];   // [2, NE] int32
    const float* Wself  = (const float*)d_in[2];
    const float* Wneigh = (const float*)d_in[3];
    const float* bsage  = (const float*)d_in[4];
    const float* Qw     = (const float*)d_in[5];
    const float* Qb     = (const float*)d_in[6];
    const int* src = ei;
    const int* dst = ei + NE;

    float* out = (float*)d_out;

    // workspace layout (~35 MB)
    float* ws   = (float*)d_ws;
    float* A    = ws;                          // NN*NH floats (also holds mean)
    float* B    = A + (size_t)NN * NH;         // NN*NH floats
    int* ibase = (int*)(B + (size_t)NN * NH);
    int* hist  = ibase;                        // 2*NN
    int* off   = hist + 2 * NN;                // 2*NN + 1
    int* cur   = off + 2 * NN + 1;             // 2*NN
    int* bsum  = cur + 2 * NN;                 // 128
    int* bpre  = bsum + 128;                   // 128
    int* csr   = bpre + 128;                   // 2*NE

    hipMemsetAsync(hist, 0, (size_t)2 * NN * sizeof(int), stream);

    hist_kernel<<<(NE + 255) / 256, 256, 0, stream>>>(src, dst, hist);
    scan_partial<<<NB, 1024, 0, stream>>>(hist, bsum);
    scan_bsums<<<1, 128, 0, stream>>>(bsum, bpre);
    scan_final<<<NB, 1024, 0, stream>>>(hist, bpre, off, cur);
    build_kernel<<<(NE + 255) / 256, 256, 0, stream>>>(src, dst, cur, csr);
    gather_mean<<<(NN + 3) / 4, 256, 0, stream>>>(X, off + NN, csr, A);
    node_gemm<<<512, 256, 0, stream>>>(X, A, Wself, Wneigh, bsage, Qw, B);
    edge_out<<<(NN + 3) / 4, 256, 0, stream>>>(A, B, Qb, off, csr, out);
}

// Round 5
// 216.890 us; speedup vs baseline: 4.2932x; 1.9468x over previous
//
#include <hip/hip_runtime.h>
#include <math.h>

#define NN 50000
#define NE 1000000
#define NH 64
#define NKEY 100000      // 2*NN combined key space (src | NN+dst)
#define SPAN 512         // keys per bucket
#define NBKT 196         // ceil(NKEY / SPAN)
#define CAP 12288        // bucket capacity (mean 10240, +20 sigma)
#define CH 34            // LDS staging entries per bucket

// ---------- binning helpers -------------------------------------------------
__device__ __forceinline__ void push_pair(int key, int val, int* cnt,
                                          unsigned* buf, int* gcnt,
                                          unsigned* __restrict__ pairs) {
    int b = key >> 9;
    unsigned pk = ((unsigned)val << 9) | (unsigned)(key & 511);
    int slot = atomicAdd(&cnt[b], 1);           // LDS atomic
    if (slot < CH) {
        buf[b * CH + slot] = pk;
    } else {                                     // rare overflow: direct path
        int g = atomicAdd(&gcnt[b], 1);
        if (g < CAP) pairs[(size_t)b * CAP + g] = pk;
    }
}

__device__ __forceinline__ void flush_bins(int* cnt, unsigned* buf, int* gcnt,
                                           unsigned* __restrict__ pairs) {
    __syncthreads();
    int b = threadIdx.x;
    if (b < NBKT) {
        int fc = cnt[b]; if (fc > CH) fc = CH;
        if (fc > 0) {
            int g = atomicAdd(&gcnt[b], fc);     // one global atomic per run
            for (int t = 0; t < fc; ++t)
                if (g + t < CAP)
                    pairs[(size_t)b * CAP + g + t] = buf[b * CH + t];
            cnt[b] = 0;
        }
    }
    __syncthreads();
}

// ---------- pass 1: LDS-staged binning of 2M (key,val) pairs ----------------
__global__ __launch_bounds__(256) void bin_pass(
    const int* __restrict__ src, const int* __restrict__ dst,
    int* __restrict__ gcnt, unsigned* __restrict__ pairs) {
    __shared__ int cnt[NBKT];
    __shared__ unsigned buf[NBKT * CH];
    for (int b = threadIdx.x; b < NBKT; b += 256) cnt[b] = 0;
    __syncthreads();
    int r = 0;
    for (int base = blockIdx.x * 256; base < NE; base += gridDim.x * 256) {
        int e = base + threadIdx.x;
        if (e < NE) {
            int s = src[e], d = dst[e];
            push_pair(s, d, cnt, buf, gcnt, pairs);       // out-edge of s
            push_pair(NN + d, s, cnt, buf, gcnt, pairs);  // in-edge of d
        }
        if ((++r & 7) == 0) flush_bins(cnt, buf, gcnt, pairs);
    }
    flush_bins(cnt, buf, gcnt, pairs);
}

// ---------- pass 2: scan 196 bucket counts ----------------------------------
__global__ __launch_bounds__(256) void bucket_scan(
    const int* __restrict__ gcnt, int* __restrict__ gbase,
    int* __restrict__ off) {
    __shared__ int tmp[256];
    int t = threadIdx.x;
    int v = (t < NBKT) ? gcnt[t] : 0;
    tmp[t] = v;
    __syncthreads();
    for (int o = 1; o < 256; o <<= 1) {
        int u = (t >= o) ? tmp[t - o] : 0;
        __syncthreads();
        tmp[t] += u;
        __syncthreads();
    }
    if (t < NBKT) gbase[t] = tmp[t] - v;   // exclusive prefix
    if (t == 0) off[NKEY] = 2 * NE;        // sentinel
}

// ---------- pass 3: per-bucket counting sort + off/csr emission -------------
__global__ __launch_bounds__(1024) void sort_pass(
    const unsigned* __restrict__ pairs, const int* __restrict__ gcnt,
    const int* __restrict__ gbase, int* __restrict__ off,
    int* __restrict__ csr) {
    __shared__ int hist[SPAN];
    __shared__ int scn[SPAN];
    int k = blockIdx.x;
    int t = threadIdx.x;
    int n = gcnt[k]; if (n > CAP) n = CAP;
    int base = gbase[k];
    const unsigned* bp = pairs + (size_t)k * CAP;

    if (t < SPAN) hist[t] = 0;
    __syncthreads();
    for (int i = t; i < n; i += 1024)
        atomicAdd(&hist[bp[i] & 511], 1);
    __syncthreads();
    if (t < SPAN) scn[t] = hist[t];
    __syncthreads();
    for (int o = 1; o < SPAN; o <<= 1) {
        int u = 0;
        if (t < SPAN && t >= o) u = scn[t - o];
        __syncthreads();
        if (t < SPAN) scn[t] += u;
        __syncthreads();
    }
    if (t < SPAN) {
        int ex = base + scn[t] - hist[t];   // absolute exclusive prefix
        int gk = k * SPAN + t;
        if (gk < NKEY) off[gk] = ex;
        scn[t] = ex;                        // reuse as cursor
    }
    __syncthreads();
    for (int i = t; i < n; i += 1024) {
        unsigned p = bp[i];
        int pos = atomicAdd(&scn[p & 511], 1);   // LDS atomic
        csr[pos] = (int)(p >> 9);                // block-local global store
    }
}

// ---------- pass 4: wave-per-node gather-mean, 8-deep ILP -------------------
__global__ __launch_bounds__(256) void gather_mean(
    const float* __restrict__ X, const int* __restrict__ off_dst,
    const int* __restrict__ csr, float* __restrict__ M) {
    int wid = (int)(((long long)blockIdx.x * blockDim.x + threadIdx.x) >> 6);
    int j = threadIdx.x & 63;
    if (wid >= NN) return;
    int e0 = off_dst[wid], e1 = off_dst[wid + 1];
    const float* Xj = X + j;
    float s0 = 0, s1 = 0, s2 = 0, s3 = 0, s4 = 0, s5 = 0, s6 = 0, s7 = 0;
    int e = e0;
    for (; e + 8 <= e1; e += 8) {
        int i0 = csr[e + 0], i1 = csr[e + 1];
        int i2 = csr[e + 2], i3 = csr[e + 3];
        int i4 = csr[e + 4], i5 = csr[e + 5];
        int i6 = csr[e + 6], i7 = csr[e + 7];
        s0 += Xj[(size_t)i0 * NH]; s1 += Xj[(size_t)i1 * NH];
        s2 += Xj[(size_t)i2 * NH]; s3 += Xj[(size_t)i3 * NH];
        s4 += Xj[(size_t)i4 * NH]; s5 += Xj[(size_t)i5 * NH];
        s6 += Xj[(size_t)i6 * NH]; s7 += Xj[(size_t)i7 * NH];
    }
    for (; e < e1; ++e) s0 += Xj[(size_t)csr[e] * NH];
    float sum = ((s0 + s1) + (s2 + s3)) + ((s4 + s5) + (s6 + s7));
    M[(size_t)wid * NH + j] = sum / fmaxf((float)(e1 - e0), 1.0f);
}

// ---------- pass 5: wave-local SAGE + projections (no inner barriers) -------
__global__ __launch_bounds__(256) void node_gemm(
    const float* __restrict__ X, float* MA /* in: mean, out: A (aliased) */,
    const float* __restrict__ Wself, const float* __restrict__ Wneigh,
    const float* __restrict__ bsage, const float* __restrict__ Qw,
    float* __restrict__ B) {
    __shared__ float sWs[4096];
    __shared__ float sWn[4096];
    __shared__ float sQ1[4096];
    __shared__ float sQ2[4096];
    __shared__ float st[4][3][64];   // per-wave x, m, h staging

    for (int i = threadIdx.x; i < 4096; i += 256) {
        sWs[i] = Wself[i];
        sWn[i] = Wneigh[i];
        sQ1[i] = Qw[i];            // rows 0..63 of Q_w
        sQ2[i] = Qw[4096 + i];     // rows 64..127
    }
    __syncthreads();

    int w = threadIdx.x >> 6;
    int j = threadIdx.x & 63;
    float bj = bsage[j];

    for (int node = blockIdx.x * 4 + w; node < NN; node += gridDim.x * 4) {
        st[w][0][j] = X[(size_t)node * NH + j];
        st[w][1][j] = MA[(size_t)node * NH + j];
        __builtin_amdgcn_wave_barrier();   // wave-synchronous LDS RAW
        float acc = bj;
        #pragma unroll
        for (int k = 0; k < 64; ++k)
            acc += st[w][0][k] * sWs[k * 64 + j] + st[w][1][k] * sWn[k * 64 + j];
        float h = fmaxf(acc, 0.0f);
        st[w][2][j] = h;
        __builtin_amdgcn_wave_barrier();
        float a = 0.0f, b = 0.0f;
        #pragma unroll
        for (int k = 0; k < 64; ++k) {
            float hk = st[w][2][k];
            a += hk * sQ1[k * 64 + j];
            b += hk * sQ2[k * 64 + j];
        }
        MA[(size_t)node * NH + j] = a;     // overwrite mean with A (1:1, safe)
        B[(size_t)node * NH + j] = b;
        __builtin_amdgcn_wave_barrier();   // keep next iter's write after reads
    }
}

// ---------- pass 6: wave-per-node out-edge reduction, 8-deep ILP ------------
__global__ __launch_bounds__(256) void edge_out(
    const float* __restrict__ A, const float* __restrict__ B,
    const float* __restrict__ Qb, const int* __restrict__ off_src,
    const int* __restrict__ csr, float* __restrict__ out) {
    int wid = (int)(((long long)blockIdx.x * blockDim.x + threadIdx.x) >> 6);
    int j = threadIdx.x & 63;
    if (wid >= NN) return;
    float aq = A[(size_t)wid * NH + j] + Qb[j];
    int e0 = off_src[wid], e1 = off_src[wid + 1];
    const float* Bj = B + j;
    float s0 = 0, s1 = 0, s2 = 0, s3 = 0, s4 = 0, s5 = 0, s6 = 0, s7 = 0;
    int e = e0;
    for (; e + 8 <= e1; e += 8) {
        int i0 = csr[e + 0], i1 = csr[e + 1];
        int i2 = csr[e + 2], i3 = csr[e + 3];
        int i4 = csr[e + 4], i5 = csr[e + 5];
        int i6 = csr[e + 6], i7 = csr[e + 7];
        float t0 = aq + Bj[(size_t)i0 * NH]; s0 += t0 * t0;
        float t1 = aq + Bj[(size_t)i1 * NH]; s1 += t1 * t1;
        float t2 = aq + Bj[(size_t)i2 * NH]; s2 += t2 * t2;
        float t3 = aq + Bj[(size_t)i3 * NH]; s3 += t3 * t3;
        float t4 = aq + Bj[(size_t)i4 * NH]; s4 += t4 * t4;
        float t5 = aq + Bj[(size_t)i5 * NH]; s5 += t5 * t5;
        float t6 = aq + Bj[(size_t)i6 * NH]; s6 += t6 * t6;
        float t7 = aq + Bj[(size_t)i7 * NH]; s7 += t7 * t7;
    }
    for (; e < e1; ++e) {
        float t = aq + Bj[(size_t)csr[e] * NH];
        s0 += t * t;
    }
    float acc = ((s0 + s1) + (s2 + s3)) + ((s4 + s5) + (s6 + s7));
    out[(size_t)wid * NH + j] = tanhf(acc / fmaxf((float)(e1 - e0), 1.0f));
}

extern "C" void kernel_launch(void* const* d_in, const int* in_sizes, int n_in,
                              void* d_out, int out_size, void* d_ws, size_t ws_size,
                              hipStream_t stream) {
    const float* X      = (const float*)d_in[0];
    const int*   ei     = (const int*)d_in[1];   // [2, NE] int32
    const float* Wself  = (const float*)d_in[2];
    const float* Wneigh = (const float*)d_in[3];
    const float* bsage  = (const float*)d_in[4];
    const float* Qw     = (const float*)d_in[5];
    const float* Qb     = (const float*)d_in[6];
    const int* src = ei;
    const int* dst = ei + NE;

    float* out = (float*)d_out;

    // workspace layout (~44 MB)
    float* A = (float*)d_ws;                         // NN*NH floats
    float* B = A + (size_t)NN * NH;                  // NN*NH floats
    unsigned* pairs = (unsigned*)(B + (size_t)NN * NH); // NBKT*CAP u32
    int* csr   = (int*)(pairs + (size_t)NBKT * CAP); // 2*NE
    int* off   = csr + 2 * NE;                       // NKEY+1
    int* gcnt  = off + NKEY + 1;                     // NBKT
    int* gbase = gcnt + NBKT;                        // NBKT

    hipMemsetAsync(gcnt, 0, NBKT * sizeof(int), stream);

    bin_pass<<<512, 256, 0, stream>>>(src, dst, gcnt, pairs);
    bucket_scan<<<1, 256, 0, stream>>>(gcnt, gbase, off);
    sort_pass<<<NBKT, 1024, 0, stream>>>(pairs, gcnt, gbase, off, csr);
    gather_mean<<<(NN + 3) / 4, 256, 0, stream>>>(X, off + NN, csr, A);
    node_gemm<<<512, 256, 0, stream>>>(X, A, Wself, Wneigh, bsage, Qw, B);
    edge_out<<<(NN + 3) / 4, 256, 0, stream>>>(A, B, Qb, off, csr, out);
}

// Round 6
// 175.487 us; speedup vs baseline: 5.3061x; 1.2359x over previous
//
#include <hip/hip_runtime.h>
#include <math.h>

#define NN 50000
#define NE 1000000
#define NH 64
#define NKEY 100000      // 2*NN combined key space (src | NN+dst)
#define SPAN 512         // keys per bucket
#define NBKT 196         // ceil(NKEY / SPAN)
#define CAP 12288        // bucket capacity (mean 10240, +20 sigma)
#define CH 34            // LDS staging entries per bucket
#define NPB 64           // nodes per block in node_gemm
#define LDT 68           // padded leading dim for transposed LDS tiles

// ---------- binning helpers -------------------------------------------------
__device__ __forceinline__ void push_pair(int key, int val, int* cnt,
                                          unsigned* buf, int* gcnt,
                                          unsigned* __restrict__ pairs) {
    int b = key >> 9;
    unsigned pk = ((unsigned)val << 9) | (unsigned)(key & 511);
    int slot = atomicAdd(&cnt[b], 1);           // LDS atomic
    if (slot < CH) {
        buf[b * CH + slot] = pk;
    } else {                                     // rare overflow: direct path
        int g = atomicAdd(&gcnt[b], 1);
        if (g < CAP) pairs[(size_t)b * CAP + g] = pk;
    }
}

__device__ __forceinline__ void flush_bins(int* cnt, unsigned* buf, int* gcnt,
                                           unsigned* __restrict__ pairs) {
    __syncthreads();
    int b = threadIdx.x;
    if (b < NBKT) {
        int fc = cnt[b]; if (fc > CH) fc = CH;
        if (fc > 0) {
            int g = atomicAdd(&gcnt[b], fc);     // one global atomic per run
            for (int t = 0; t < fc; ++t)
                if (g + t < CAP)
                    pairs[(size_t)b * CAP + g + t] = buf[b * CH + t];
            cnt[b] = 0;
        }
    }
    __syncthreads();
}

// ---------- pass 1: LDS-staged binning of 2M (key,val) pairs ----------------
__global__ __launch_bounds__(256) void bin_pass(
    const int* __restrict__ src, const int* __restrict__ dst,
    int* __restrict__ gcnt, unsigned* __restrict__ pairs) {
    __shared__ int cnt[NBKT];
    __shared__ unsigned buf[NBKT * CH];
    for (int b = threadIdx.x; b < NBKT; b += 256) cnt[b] = 0;
    __syncthreads();
    int r = 0;
    for (int base = blockIdx.x * 256; base < NE; base += gridDim.x * 256) {
        int e = base + threadIdx.x;
        if (e < NE) {
            int s = src[e], d = dst[e];
            push_pair(s, d, cnt, buf, gcnt, pairs);       // out-edge of s
            push_pair(NN + d, s, cnt, buf, gcnt, pairs);  // in-edge of d
        }
        if ((++r & 7) == 0) flush_bins(cnt, buf, gcnt, pairs);
    }
    flush_bins(cnt, buf, gcnt, pairs);
}

// ---------- pass 2: scan 196 bucket counts ----------------------------------
__global__ __launch_bounds__(256) void bucket_scan(
    const int* __restrict__ gcnt, int* __restrict__ gbase,
    int* __restrict__ off) {
    __shared__ int tmp[256];
    int t = threadIdx.x;
    int v = (t < NBKT) ? gcnt[t] : 0;
    tmp[t] = v;
    __syncthreads();
    for (int o = 1; o < 256; o <<= 1) {
        int u = (t >= o) ? tmp[t - o] : 0;
        __syncthreads();
        tmp[t] += u;
        __syncthreads();
    }
    if (t < NBKT) gbase[t] = tmp[t] - v;   // exclusive prefix
    if (t == 0) off[NKEY] = 2 * NE;        // sentinel
}

// ---------- pass 3: per-bucket counting sort + off/csr emission -------------
__global__ __launch_bounds__(1024) void sort_pass(
    const unsigned* __restrict__ pairs, const int* __restrict__ gcnt,
    const int* __restrict__ gbase, int* __restrict__ off,
    int* __restrict__ csr) {
    __shared__ int hist[SPAN];
    __shared__ int scn[SPAN];
    int k = blockIdx.x;
    int t = threadIdx.x;
    int n = gcnt[k]; if (n > CAP) n = CAP;
    int base = gbase[k];
    const unsigned* bp = pairs + (size_t)k * CAP;

    if (t < SPAN) hist[t] = 0;
    __syncthreads();
    for (int i = t; i < n; i += 1024)
        atomicAdd(&hist[bp[i] & 511], 1);
    __syncthreads();
    if (t < SPAN) scn[t] = hist[t];
    __syncthreads();
    for (int o = 1; o < SPAN; o <<= 1) {
        int u = 0;
        if (t < SPAN && t >= o) u = scn[t - o];
        __syncthreads();
        if (t < SPAN) scn[t] += u;
        __syncthreads();
    }
    if (t < SPAN) {
        int ex = base + scn[t] - hist[t];   // absolute exclusive prefix
        int gk = k * SPAN + t;
        if (gk < NKEY) off[gk] = ex;
        scn[t] = ex;                        // reuse as cursor
    }
    __syncthreads();
    for (int i = t; i < n; i += 1024) {
        unsigned p = bp[i];
        int pos = atomicAdd(&scn[p & 511], 1);   // LDS atomic
        csr[pos] = (int)(p >> 9);                // block-local global store
    }
}

// ---------- pass 4: wave-per-node gather-mean, 8-deep ILP -------------------
__global__ __launch_bounds__(256) void gather_mean(
    const float* __restrict__ X, const int* __restrict__ off_dst,
    const int* __restrict__ csr, float* __restrict__ M) {
    int wid = (int)(((long long)blockIdx.x * blockDim.x + threadIdx.x) >> 6);
    int j = threadIdx.x & 63;
    if (wid >= NN) return;
    int e0 = off_dst[wid], e1 = off_dst[wid + 1];
    const float* Xj = X + j;
    float s0 = 0, s1 = 0, s2 = 0, s3 = 0, s4 = 0, s5 = 0, s6 = 0, s7 = 0;
    int e = e0;
    for (; e + 8 <= e1; e += 8) {
        int i0 = csr[e + 0], i1 = csr[e + 1];
        int i2 = csr[e + 2], i3 = csr[e + 3];
        int i4 = csr[e + 4], i5 = csr[e + 5];
        int i6 = csr[e + 6], i7 = csr[e + 7];
        s0 += Xj[(size_t)i0 * NH]; s1 += Xj[(size_t)i1 * NH];
        s2 += Xj[(size_t)i2 * NH]; s3 += Xj[(size_t)i3 * NH];
        s4 += Xj[(size_t)i4 * NH]; s5 += Xj[(size_t)i5 * NH];
        s6 += Xj[(size_t)i6 * NH]; s7 += Xj[(size_t)i7 * NH];
    }
    for (; e < e1; ++e) s0 += Xj[(size_t)csr[e] * NH];
    float sum = ((s0 + s1) + (s2 + s3)) + ((s4 + s5) + (s6 + s7));
    M[(size_t)wid * NH + j] = sum / fmaxf((float)(e1 - e0), 1.0f);
}

// ---------- pass 5: register-tiled node GEMM (4x4 tile per thread) ----------
// Block: 64 nodes, 256 threads. Phase 1: h = relu(x*Ws + m*Wn + b).
// Phase 2: A = h*Q1, B = h*Q2 (hT reuses xT slot; Q1/Q2 re-staged over Ws/Wn).
__global__ __launch_bounds__(256) void node_gemm(
    const float* __restrict__ X, float* MA /* in: mean, out: A (aliased) */,
    const float* __restrict__ Wself, const float* __restrict__ Wneigh,
    const float* __restrict__ bsage, const float* __restrict__ Qw,
    float* __restrict__ B) {
    __shared__ __align__(16) float xT[64 * LDT];  // xT[k][n]; later hT[j][n]
    __shared__ __align__(16) float mT[64 * LDT];  // mT[k][n]
    __shared__ __align__(16) float sWa[4096];     // Ws, later Q1 (row-major [k][j])
    __shared__ __align__(16) float sWb[4096];     // Wn, later Q2

    const int T  = threadIdx.x;
    const int tj = T & 15;          // col group: cols 4*tj..4*tj+3
    const int tn = T >> 4;          // node group: nodes 4*tn..4*tn+3
    const int nbase = blockIdx.x * NPB;

    // stage Ws, Wn (1024 float4)
    #pragma unroll
    for (int r = 0; r < 4; ++r) {
        int i = r * 256 + T;
        ((float4*)sWa)[i] = ((const float4*)Wself)[i];
        ((float4*)sWb)[i] = ((const float4*)Wneigh)[i];
    }
    // stage xT, mT transposed (clamp OOB node to NN-1; stores are guarded)
    #pragma unroll
    for (int r = 0; r < 4; ++r) {
        int F = r * 256 + T;        // 0..1023
        int node = F >> 4;          // 0..63
        int k0 = (F & 15) * 4;
        int gn = nbase + node; if (gn > NN - 1) gn = NN - 1;
        float4 xv = *(const float4*)&X[(size_t)gn * NH + k0];
        float4 mv = *(const float4*)&MA[(size_t)gn * NH + k0];
        xT[(k0 + 0) * LDT + node] = xv.x;
        xT[(k0 + 1) * LDT + node] = xv.y;
        xT[(k0 + 2) * LDT + node] = xv.z;
        xT[(k0 + 3) * LDT + node] = xv.w;
        mT[(k0 + 0) * LDT + node] = mv.x;
        mT[(k0 + 1) * LDT + node] = mv.y;
        mT[(k0 + 2) * LDT + node] = mv.z;
        mT[(k0 + 3) * LDT + node] = mv.w;
    }
    __syncthreads();

    // ---- phase 1: SAGE ----
    float4 bv = ((const float4*)bsage)[tj];
    const float* bp = (const float*)&bv;
    float acc[4][4];
    #pragma unroll
    for (int ni = 0; ni < 4; ++ni)
        #pragma unroll
        for (int ji = 0; ji < 4; ++ji) acc[ni][ji] = bp[ji];

    #pragma unroll 8
    for (int k = 0; k < 64; ++k) {
        float4 xv4 = *(const float4*)&xT[k * LDT + tn * 4];
        float4 mv4 = *(const float4*)&mT[k * LDT + tn * 4];
        float4 wa4 = ((const float4*)sWa)[k * 16 + tj];
        float4 wb4 = ((const float4*)sWb)[k * 16 + tj];
        const float* xv = (const float*)&xv4;
        const float* mv = (const float*)&mv4;
        const float* wa = (const float*)&wa4;
        const float* wb = (const float*)&wb4;
        #pragma unroll
        for (int ni = 0; ni < 4; ++ni)
            #pragma unroll
            for (int ji = 0; ji < 4; ++ji)
                acc[ni][ji] += xv[ni] * wa[ji] + mv[ni] * wb[ji];
    }
    __syncthreads();   // all xT/mT + Ws/Wn reads done

    // write hT[j][n] = relu(acc) into xT slot; re-stage Q1/Q2
    #pragma unroll
    for (int ni = 0; ni < 4; ++ni)
        #pragma unroll
        for (int ji = 0; ji < 4; ++ji)
            xT[(tj * 4 + ji) * LDT + tn * 4 + ni] = fmaxf(acc[ni][ji], 0.0f);
    #pragma unroll
    for (int r = 0; r < 4; ++r) {
        int i = r * 256 + T;
        ((float4*)sWa)[i] = ((const float4*)Qw)[i];           // rows 0..63
        ((float4*)sWb)[i] = ((const float4*)(Qw + 4096))[i];  // rows 64..127
    }
    __syncthreads();

    // ---- phase 2: A = h Q1, B = h Q2 ----
    float aA[4][4], aB[4][4];
    #pragma unroll
    for (int ni = 0; ni < 4; ++ni)
        #pragma unroll
        for (int ji = 0; ji < 4; ++ji) { aA[ni][ji] = 0.0f; aB[ni][ji] = 0.0f; }

    #pragma unroll 8
    for (int j = 0; j < 64; ++j) {
        float4 hv4 = *(const float4*)&xT[j * LDT + tn * 4];
        float4 q14 = ((const float4*)sWa)[j * 16 + tj];
        float4 q24 = ((const float4*)sWb)[j * 16 + tj];
        const float* hv = (const float*)&hv4;
        const float* q1 = (const float*)&q14;
        const float* q2 = (const float*)&q24;
        #pragma unroll
        for (int ni = 0; ni < 4; ++ni)
            #pragma unroll
            for (int ji = 0; ji < 4; ++ji) {
                aA[ni][ji] += hv[ni] * q1[ji];
                aB[ni][ji] += hv[ni] * q2[ji];
            }
    }

    // store A (over mean) and B
    #pragma unroll
    for (int ni = 0; ni < 4; ++ni) {
        int gn = nbase + tn * 4 + ni;
        if (gn < NN) {
            float4 va, vb;
            va.x = aA[ni][0]; va.y = aA[ni][1]; va.z = aA[ni][2]; va.w = aA[ni][3];
            vb.x = aB[ni][0]; vb.y = aB[ni][1]; vb.z = aB[ni][2]; vb.w = aB[ni][3];
            *(float4*)&MA[(size_t)gn * NH + tj * 4] = va;
            *(float4*)&B[(size_t)gn * NH + tj * 4] = vb;
        }
    }
}

// ---------- pass 6: wave-per-node out-edge reduction, 8-deep ILP ------------
__global__ __launch_bounds__(256) void edge_out(
    const float* __restrict__ A, const float* __restrict__ B,
    const float* __restrict__ Qb, const int* __restrict__ off_src,
    const int* __restrict__ csr, float* __restrict__ out) {
    int wid = (int)(((long long)blockIdx.x * blockDim.x + threadIdx.x) >> 6);
    int j = threadIdx.x & 63;
    if (wid >= NN) return;
    float aq = A[(size_t)wid * NH + j] + Qb[j];
    int e0 = off_src[wid], e1 = off_src[wid + 1];
    const float* Bj = B + j;
    float s0 = 0, s1 = 0, s2 = 0, s3 = 0, s4 = 0, s5 = 0, s6 = 0, s7 = 0;
    int e = e0;
    for (; e + 8 <= e1; e += 8) {
        int i0 = csr[e + 0], i1 = csr[e + 1];
        int i2 = csr[e + 2], i3 = csr[e + 3];
        int i4 = csr[e + 4], i5 = csr[e + 5];
        int i6 = csr[e + 6], i7 = csr[e + 7];
        float t0 = aq + Bj[(size_t)i0 * NH]; s0 += t0 * t0;
        float t1 = aq + Bj[(size_t)i1 * NH]; s1 += t1 * t1;
        float t2 = aq + Bj[(size_t)i2 * NH]; s2 += t2 * t2;
        float t3 = aq + Bj[(size_t)i3 * NH]; s3 += t3 * t3;
        float t4 = aq + Bj[(size_t)i4 * NH]; s4 += t4 * t4;
        float t5 = aq + Bj[(size_t)i5 * NH]; s5 += t5 * t5;
        float t6 = aq + Bj[(size_t)i6 * NH]; s6 += t6 * t6;
        float t7 = aq + Bj[(size_t)i7 * NH]; s7 += t7 * t7;
    }
    for (; e < e1; ++e) {
        float t = aq + Bj[(size_t)csr[e] * NH];
        s0 += t * t;
    }
    float acc = ((s0 + s1) + (s2 + s3)) + ((s4 + s5) + (s6 + s7));
    out[(size_t)wid * NH + j] = tanhf(acc / fmaxf((float)(e1 - e0), 1.0f));
}

extern "C" void kernel_launch(void* const* d_in, const int* in_sizes, int n_in,
                              void* d_out, int out_size, void* d_ws, size_t ws_size,
                              hipStream_t stream) {
    const float* X      = (const float*)d_in[0];
    const int*   ei     = (const int*)d_in[1];   // [2, NE] int32
    const float* Wself  = (const float*)d_in[2];
    const float* Wneigh = (const float*)d_in[3];
    const float* bsage  = (const float*)d_in[4];
    const float* Qw     = (const float*)d_in[5];
    const float* Qb     = (const float*)d_in[6];
    const int* src = ei;
    const int* dst = ei + NE;

    float* out = (float*)d_out;

    // workspace layout (~44 MB)
    float* A = (float*)d_ws;                         // NN*NH floats
    float* B = A + (size_t)NN * NH;                  // NN*NH floats
    unsigned* pairs = (unsigned*)(B + (size_t)NN * NH); // NBKT*CAP u32
    int* csr   = (int*)(pairs + (size_t)NBKT * CAP); // 2*NE
    int* off   = csr + 2 * NE;                       // NKEY+1
    int* gcnt  = off + NKEY + 1;                     // NBKT
    int* gbase = gcnt + NBKT;                        // NBKT

    hipMemsetAsync(gcnt, 0, NBKT * sizeof(int), stream);

    bin_pass<<<512, 256, 0, stream>>>(src, dst, gcnt, pairs);
    bucket_scan<<<1, 256, 0, stream>>>(gcnt, gbase, off);
    sort_pass<<<NBKT, 1024, 0, stream>>>(pairs, gcnt, gbase, off, csr);
    gather_mean<<<(NN + 3) / 4, 256, 0, stream>>>(X, off + NN, csr, A);
    node_gemm<<<(NN + NPB - 1) / NPB, 256, 0, stream>>>(X, A, Wself, Wneigh,
                                                        bsage, Qw, B);
    edge_out<<<(NN + 3) / 4, 256, 0, stream>>>(A, B, Qb, off, csr, out);
}